// Round 2
// baseline (188.448 us; speedup 1.0000x reference)
//
#include <hip/hip_runtime.h>
#include <hip/hip_bf16.h>

// 2D DCT-II (4096x4096 fp32) via Makhoul reorder + radix-4 LDS FFT + on-device
// expk twiddle.  Correctness-first round: ALL twiddles via precise sincosf
// (radians) and expk computed on device (harness complex64 layout unknown).
// Plan: dct_rows(x -> out) ; transpose(out -> ws) ; dct_rows(ws -> ws) ;
//       transpose(ws -> out).  d_ws needs 64 MB.

#define L4096 4096
#define LDSPAD(i) ((i) + ((i) >> 5))   // break power-of-2 bank strides

__device__ __forceinline__ int digitrev12(int n) {
    // reverse 6 base-4 digits of a 12-bit index
    int r = 0;
#pragma unroll
    for (int i = 0; i < 6; ++i) { r = (r << 2) | (n & 3); n >>= 2; }
    return r;
}

__global__ __launch_bounds__(256)
void dct_rows_kernel(const float* __restrict__ in, float* __restrict__ out) {
    // One 4096-point complex FFT per block, in LDS.
    __shared__ float2 lds[L4096 + (L4096 >> 5)];   // 4224 float2 = 33792 B

    const int row = blockIdx.x;
    const int tid = threadIdx.x;
    const float* xrow = in + (size_t)row * L4096;

    // Load with Makhoul even/odd reorder fused with base-4 digit reversal.
    // v[n] = x[2n] (n<2048) else x[8191-2n]; store v[n] at digitrev(n).
#pragma unroll
    for (int w = 0; w < 16; ++w) {
        int n = w * 256 + tid;
        int src = (n < 2048) ? (2 * n) : (8191 - 2 * n);
        float v = xrow[src];
        int p = digitrev12(n);
        lds[LDSPAD(p)] = make_float2(v, 0.0f);
    }
    __syncthreads();

    // 6 radix-4 DIT stages (forward FFT, e^{-2*pi*i/N} convention)
#pragma unroll
    for (int s = 0; s < 6; ++s) {
        const int Q = 1 << (2 * s);
        const float negTwoPiInvLs = -6.283185307179586f / (float)(4 << (2 * s));
#pragma unroll
        for (int w = 0; w < 4; ++w) {
            int u = w * 256 + tid;              // butterfly id, 0..1023
            int j = u & (Q - 1);
            int g = u >> (2 * s);
            int i0 = (g << (2 * s + 2)) + j;
            int p0 = LDSPAD(i0);
            int p1 = LDSPAD(i0 + Q);
            int p2 = LDSPAD(i0 + 2 * Q);
            int p3 = LDSPAD(i0 + 3 * Q);
            float2 a = lds[p0];
            float2 b = lds[p1];
            float2 c = lds[p2];
            float2 d = lds[p3];

            float ang = (float)j * negTwoPiInvLs;   // in (-pi/2, 0]
            float c1, s1;
            sincosf(ang, &s1, &c1);                 // precise libm, radians
            float c2 = c1 * c1 - s1 * s1, s2 = 2.0f * c1 * s1;       // w1^2
            float c3 = c1 * c2 - s1 * s2, s3 = c1 * s2 + s1 * c2;    // w1^3

            float2 B = make_float2(b.x * c1 - b.y * s1, b.x * s1 + b.y * c1);
            float2 C = make_float2(c.x * c2 - c.y * s2, c.x * s2 + c.y * c2);
            float2 D = make_float2(d.x * c3 - d.y * s3, d.x * s3 + d.y * c3);

            float t0x = a.x + C.x, t0y = a.y + C.y;
            float t1x = a.x - C.x, t1y = a.y - C.y;
            float t2x = B.x + D.x, t2y = B.y + D.y;
            float t3x = B.x - D.x, t3y = B.y - D.y;

            lds[p0] = make_float2(t0x + t2x, t0y + t2y);
            lds[p1] = make_float2(t1x + t3y, t1y - t3x);   // t1 + (-i)*t3
            lds[p2] = make_float2(t0x - t2x, t0y - t2y);
            lds[p3] = make_float2(t1x - t3y, t1y + t3x);   // t1 + (+i)*t3
        }
        __syncthreads();
    }

    // y[k] = Re(V[k] * exp(-i*pi*k/(2*4096)))
    //      = V.x*cos(th) + V.y*sin(th),  th = pi*k/8192
    float* orow = out + (size_t)row * L4096;
#pragma unroll
    for (int w = 0; w < 16; ++w) {
        int k = w * 256 + tid;
        float2 V = lds[LDSPAD(k)];
        float th = (float)k * 3.8349519697141029e-4f;   // pi/8192
        float sk, ck;
        sincosf(th, &sk, &ck);
        orow[k] = V.x * ck + V.y * sk;
    }
}

__global__ __launch_bounds__(256)
void transpose_kernel(const float* __restrict__ in, float* __restrict__ out) {
    __shared__ float tile[32][33];
    const int bx = blockIdx.x, by = blockIdx.y;
    const int tx = threadIdx.x, ty = threadIdx.y;   // (32, 8)

#pragma unroll
    for (int i = 0; i < 32; i += 8) {
        tile[ty + i][tx] = in[(size_t)(by * 32 + ty + i) * L4096 + bx * 32 + tx];
    }
    __syncthreads();
#pragma unroll
    for (int i = 0; i < 32; i += 8) {
        out[(size_t)(bx * 32 + ty + i) * L4096 + by * 32 + tx] = tile[tx][ty + i];
    }
}

extern "C" void kernel_launch(void* const* d_in, const int* in_sizes, int n_in,
                              void* d_out, int out_size, void* d_ws, size_t ws_size,
                              hipStream_t stream) {
    const float* x = (const float*)d_in[0];
    float* out = (float*)d_out;
    float* ws  = (float*)d_ws;   // needs 64 MB

    dim3 tgrid(L4096 / 32, L4096 / 32);
    dim3 tblk(32, 8);

    // 1) DCT along rows (axis -1, length N) : x -> out
    dct_rows_kernel<<<L4096, 256, 0, stream>>>(x, out);
    // 2) transpose: out -> ws
    transpose_kernel<<<tgrid, tblk, 0, stream>>>(out, ws);
    // 3) DCT along rows of transposed (= original axis 0, length M), in place
    dct_rows_kernel<<<L4096, 256, 0, stream>>>(ws, ws);
    // 4) transpose back: ws -> out
    transpose_kernel<<<tgrid, tblk, 0, stream>>>(ws, out);
}

// Round 3
// 165.272 us; speedup vs baseline: 1.1402x; 1.1402x over previous
//
#include <hip/hip_runtime.h>
#include <hip/hip_bf16.h>

// 2D DCT-II (4096x4096 fp32) via Makhoul reorder + radix-4 LDS FFT + on-device
// expk twiddle.  Round 2: all twiddles via fast hardware __sincosf
// (v_sin_f32/v_cos_f32) — angles are in (-pi/2, 0], well within the accurate
// range; precise-libm round passed with absmax 32 vs threshold 231.
// Plan: dct_rows(x -> out) ; transpose(out -> ws) ; dct_rows(ws -> ws) ;
//       transpose(ws -> out).  d_ws needs 64 MB.

#define L4096 4096
#define LDSPAD(i) ((i) + ((i) >> 5))   // break power-of-2 bank strides

__device__ __forceinline__ int digitrev12(int n) {
    // reverse 6 base-4 digits of a 12-bit index
    int r = 0;
#pragma unroll
    for (int i = 0; i < 6; ++i) { r = (r << 2) | (n & 3); n >>= 2; }
    return r;
}

__global__ __launch_bounds__(256)
void dct_rows_kernel(const float* __restrict__ in, float* __restrict__ out) {
    // One 4096-point complex FFT per block, in LDS.
    __shared__ float2 lds[L4096 + (L4096 >> 5)];   // 4224 float2 = 33792 B

    const int row = blockIdx.x;
    const int tid = threadIdx.x;
    const float* xrow = in + (size_t)row * L4096;

    // Load with Makhoul even/odd reorder fused with base-4 digit reversal.
    // v[n] = x[2n] (n<2048) else x[8191-2n]; store v[n] at digitrev(n).
#pragma unroll
    for (int w = 0; w < 16; ++w) {
        int n = w * 256 + tid;
        int src = (n < 2048) ? (2 * n) : (8191 - 2 * n);
        float v = xrow[src];
        int p = digitrev12(n);
        lds[LDSPAD(p)] = make_float2(v, 0.0f);
    }
    __syncthreads();

    // 6 radix-4 DIT stages (forward FFT, e^{-2*pi*i/N} convention)
#pragma unroll
    for (int s = 0; s < 6; ++s) {
        const int Q = 1 << (2 * s);
        const float negTwoPiInvLs = -6.283185307179586f / (float)(4 << (2 * s));
#pragma unroll
        for (int w = 0; w < 4; ++w) {
            int u = w * 256 + tid;              // butterfly id, 0..1023
            int j = u & (Q - 1);
            int g = u >> (2 * s);
            int i0 = (g << (2 * s + 2)) + j;
            int p0 = LDSPAD(i0);
            int p1 = LDSPAD(i0 + Q);
            int p2 = LDSPAD(i0 + 2 * Q);
            int p3 = LDSPAD(i0 + 3 * Q);
            float2 a = lds[p0];
            float2 b = lds[p1];
            float2 c = lds[p2];
            float2 d = lds[p3];

            float ang = (float)j * negTwoPiInvLs;   // in (-pi/2, 0]
            float c1, s1;
            __sincosf(ang, &s1, &c1);               // v_sin_f32 / v_cos_f32
            float c2 = c1 * c1 - s1 * s1, s2 = 2.0f * c1 * s1;       // w1^2
            float c3 = c1 * c2 - s1 * s2, s3 = c1 * s2 + s1 * c2;    // w1^3

            float2 B = make_float2(b.x * c1 - b.y * s1, b.x * s1 + b.y * c1);
            float2 C = make_float2(c.x * c2 - c.y * s2, c.x * s2 + c.y * c2);
            float2 D = make_float2(d.x * c3 - d.y * s3, d.x * s3 + d.y * c3);

            float t0x = a.x + C.x, t0y = a.y + C.y;
            float t1x = a.x - C.x, t1y = a.y - C.y;
            float t2x = B.x + D.x, t2y = B.y + D.y;
            float t3x = B.x - D.x, t3y = B.y - D.y;

            lds[p0] = make_float2(t0x + t2x, t0y + t2y);
            lds[p1] = make_float2(t1x + t3y, t1y - t3x);   // t1 + (-i)*t3
            lds[p2] = make_float2(t0x - t2x, t0y - t2y);
            lds[p3] = make_float2(t1x - t3y, t1y + t3x);   // t1 + (+i)*t3
        }
        __syncthreads();
    }

    // y[k] = Re(V[k] * exp(-i*pi*k/(2*4096)))
    //      = V.x*cos(th) + V.y*sin(th),  th = pi*k/8192
    float* orow = out + (size_t)row * L4096;
#pragma unroll
    for (int w = 0; w < 16; ++w) {
        int k = w * 256 + tid;
        float2 V = lds[LDSPAD(k)];
        float th = (float)k * 3.8349519697141029e-4f;   // pi/8192
        float sk, ck;
        __sincosf(th, &sk, &ck);
        orow[k] = V.x * ck + V.y * sk;
    }
}

__global__ __launch_bounds__(256)
void transpose_kernel(const float* __restrict__ in, float* __restrict__ out) {
    __shared__ float tile[32][33];
    const int bx = blockIdx.x, by = blockIdx.y;
    const int tx = threadIdx.x, ty = threadIdx.y;   // (32, 8)

#pragma unroll
    for (int i = 0; i < 32; i += 8) {
        tile[ty + i][tx] = in[(size_t)(by * 32 + ty + i) * L4096 + bx * 32 + tx];
    }
    __syncthreads();
#pragma unroll
    for (int i = 0; i < 32; i += 8) {
        out[(size_t)(bx * 32 + ty + i) * L4096 + by * 32 + tx] = tile[tx][ty + i];
    }
}

extern "C" void kernel_launch(void* const* d_in, const int* in_sizes, int n_in,
                              void* d_out, int out_size, void* d_ws, size_t ws_size,
                              hipStream_t stream) {
    const float* x = (const float*)d_in[0];
    float* out = (float*)d_out;
    float* ws  = (float*)d_ws;   // needs 64 MB

    dim3 tgrid(L4096 / 32, L4096 / 32);
    dim3 tblk(32, 8);

    // 1) DCT along rows (axis -1, length N) : x -> out
    dct_rows_kernel<<<L4096, 256, 0, stream>>>(x, out);
    // 2) transpose: out -> ws
    transpose_kernel<<<tgrid, tblk, 0, stream>>>(out, ws);
    // 3) DCT along rows of transposed (= original axis 0, length M), in place
    dct_rows_kernel<<<L4096, 256, 0, stream>>>(ws, ws);
    // 4) transpose back: ws -> out
    transpose_kernel<<<tgrid, tblk, 0, stream>>>(ws, out);
}

// Round 4
// 119.788 us; speedup vs baseline: 1.5732x; 1.3797x over previous
//
#include <hip/hip_runtime.h>
#include <hip/hip_bf16.h>

// 2D DCT-II (4096x4096 fp32) via Makhoul reorder + radix-4 LDS FFT + on-device
// expk twiddle.  Round 3: TWO real rows packed per complex FFT
// (z = rowA + i*rowB, split spectra via conjugate symmetry) -> half the FFT
// work per pass.  Twiddles via __sincosf (passed R2 with absmax 32 vs 231).
// Plan: dct2(x -> out) ; transpose(out -> ws) ; dct2(ws -> ws) ;
//       transpose(ws -> out).  d_ws needs 64 MB.

#define L4096 4096
#define LDSPAD(i) ((i) + ((i) >> 5))   // break power-of-2 bank strides

__device__ __forceinline__ int digitrev12(int n) {
    // reverse 6 base-4 digits of a 12-bit index
    int r = 0;
#pragma unroll
    for (int i = 0; i < 6; ++i) { r = (r << 2) | (n & 3); n >>= 2; }
    return r;
}

__global__ __launch_bounds__(256)
void dct_rows2_kernel(const float* __restrict__ in, float* __restrict__ out) {
    // One 4096-point complex FFT per block = DCT of TWO real rows.
    __shared__ float2 lds[L4096 + (L4096 >> 5)];   // 4224 float2 = 33792 B

    const int r0 = blockIdx.x * 2;
    const int tid = threadIdx.x;
    const float* rowA = in + (size_t)r0 * L4096;
    const float* rowB = rowA + L4096;

    // Makhoul even/odd reorder fused with base-4 digit reversal.
    // v[n] = x[2n] (n<2048) else x[8191-2n]; z[n] = vA[n] + i*vB[n].
#pragma unroll
    for (int w = 0; w < 16; ++w) {
        int n = w * 256 + tid;
        int src = (n < 2048) ? (2 * n) : (8191 - 2 * n);
        float va = rowA[src];
        float vb = rowB[src];
        lds[LDSPAD(digitrev12(n))] = make_float2(va, vb);
    }
    __syncthreads();

    // 6 radix-4 DIT stages (forward FFT, e^{-2*pi*i/N} convention)
#pragma unroll
    for (int s = 0; s < 6; ++s) {
        const int Q = 1 << (2 * s);
        const float negTwoPiInvLs = -6.283185307179586f / (float)(4 << (2 * s));
#pragma unroll
        for (int w = 0; w < 4; ++w) {
            int u = w * 256 + tid;              // butterfly id, 0..1023
            int j = u & (Q - 1);
            int g = u >> (2 * s);
            int i0 = (g << (2 * s + 2)) + j;
            int p0 = LDSPAD(i0);
            int p1 = LDSPAD(i0 + Q);
            int p2 = LDSPAD(i0 + 2 * Q);
            int p3 = LDSPAD(i0 + 3 * Q);
            float2 a = lds[p0];
            float2 b = lds[p1];
            float2 c = lds[p2];
            float2 d = lds[p3];

            float c1, s1, c2, s2, c3, s3;
            if (s == 0) {                       // j==0 always: w=1 (folds at compile time)
                c1 = 1.0f; s1 = 0.0f; c2 = 1.0f; s2 = 0.0f; c3 = 1.0f; s3 = 0.0f;
            } else {
                float ang = (float)j * negTwoPiInvLs;   // in (-pi/2, 0]
                __sincosf(ang, &s1, &c1);               // v_sin_f32 / v_cos_f32
                c2 = c1 * c1 - s1 * s1; s2 = 2.0f * c1 * s1;       // w1^2
                c3 = c1 * c2 - s1 * s2; s3 = c1 * s2 + s1 * c2;    // w1^3
            }

            float2 B = make_float2(b.x * c1 - b.y * s1, b.x * s1 + b.y * c1);
            float2 C = make_float2(c.x * c2 - c.y * s2, c.x * s2 + c.y * c2);
            float2 D = make_float2(d.x * c3 - d.y * s3, d.x * s3 + d.y * c3);

            float t0x = a.x + C.x, t0y = a.y + C.y;
            float t1x = a.x - C.x, t1y = a.y - C.y;
            float t2x = B.x + D.x, t2y = B.y + D.y;
            float t3x = B.x - D.x, t3y = B.y - D.y;

            lds[p0] = make_float2(t0x + t2x, t0y + t2y);
            lds[p1] = make_float2(t1x + t3y, t1y - t3x);   // t1 + (-i)*t3
            lds[p2] = make_float2(t0x - t2x, t0y - t2y);
            lds[p3] = make_float2(t1x - t3y, t1y + t3x);   // t1 + (+i)*t3
        }
        __syncthreads();
    }

    // Split packed spectrum and apply expk:
    //   A[k] = 0.5*(Z[k] + conj(Z[N-k]))     (spectrum of rowA)
    //   B[k] = -0.5i*(Z[k] - conj(Z[N-k]))   (spectrum of rowB)
    //   y[k] = V.x*cos(th) + V.y*sin(th),    th = pi*k/8192
    float* outA = out + (size_t)r0 * L4096;
    float* outB = outA + L4096;
#pragma unroll
    for (int w = 0; w < 16; ++w) {
        int k = w * 256 + tid;
        float2 Zk = lds[LDSPAD(k)];
        int m = (L4096 - k) & (L4096 - 1);
        float2 Zm = lds[LDSPAD(m)];

        float vax = 0.5f * (Zk.x + Zm.x);
        float vay = 0.5f * (Zk.y - Zm.y);
        float vbx = 0.5f * (Zk.y + Zm.y);
        float vby = 0.5f * (Zm.x - Zk.x);

        float th = (float)k * 3.8349519697141029e-4f;   // pi/8192
        float sk, ck;
        __sincosf(th, &sk, &ck);
        outA[k] = vax * ck + vay * sk;
        outB[k] = vbx * ck + vby * sk;
    }
}

__global__ __launch_bounds__(256)
void transpose_kernel(const float* __restrict__ in, float* __restrict__ out) {
    __shared__ float tile[32][33];
    const int bx = blockIdx.x, by = blockIdx.y;
    const int tx = threadIdx.x, ty = threadIdx.y;   // (32, 8)

#pragma unroll
    for (int i = 0; i < 32; i += 8) {
        tile[ty + i][tx] = in[(size_t)(by * 32 + ty + i) * L4096 + bx * 32 + tx];
    }
    __syncthreads();
#pragma unroll
    for (int i = 0; i < 32; i += 8) {
        out[(size_t)(bx * 32 + ty + i) * L4096 + by * 32 + tx] = tile[tx][ty + i];
    }
}

extern "C" void kernel_launch(void* const* d_in, const int* in_sizes, int n_in,
                              void* d_out, int out_size, void* d_ws, size_t ws_size,
                              hipStream_t stream) {
    const float* x = (const float*)d_in[0];
    float* out = (float*)d_out;
    float* ws  = (float*)d_ws;   // needs 64 MB

    dim3 tgrid(L4096 / 32, L4096 / 32);
    dim3 tblk(32, 8);

    // 1) DCT along rows (axis -1, length N) : x -> out   (2 rows per block)
    dct_rows2_kernel<<<L4096 / 2, 256, 0, stream>>>(x, out);
    // 2) transpose: out -> ws
    transpose_kernel<<<tgrid, tblk, 0, stream>>>(out, ws);
    // 3) DCT along rows of transposed (= original axis 0), in place
    dct_rows2_kernel<<<L4096 / 2, 256, 0, stream>>>(ws, ws);
    // 4) transpose back: ws -> out
    transpose_kernel<<<tgrid, tblk, 0, stream>>>(ws, out);
}

// Round 5
// 110.765 us; speedup vs baseline: 1.7013x; 1.0815x over previous
//
#include <hip/hip_runtime.h>
#include <hip/hip_bf16.h>

// 2D DCT-II (4096x4096 fp32), Makhoul reorder + radix-4 LDS FFT, 2 real rows
// packed per complex FFT.  Round 4: fuse radix-4 stage PAIRS into registers
// (radix-16 per LDS round-trip: 3 round-trips, 4 barriers, 144 LDS ops/thread
// vs 240) and replace pad with XOR bank-swizzle phi(e)=e^(((e>>4)^(e>>8))&15)
// (verified bank-uniform for every access shape; bijective -> LDS = 32 KB
// exactly -> 5 blocks/CU).  float2 input loads: x[2n],x[2n+1] give v[n] and
// v[4095-n] (rev(4095-n) = 4095-rev(n)).
// Plan: dct2(x->out) ; transpose(out->ws) ; dct2(ws->ws) ; transpose(ws->out).

#define L 4096

__device__ __forceinline__ int SWZ(int e) {
    return e ^ (((e >> 4) ^ (e >> 8)) & 15);
}

__device__ __forceinline__ int digitrev12(int n) {
    int r = 0;
#pragma unroll
    for (int i = 0; i < 6; ++i) { r = (r << 2) | (n & 3); n >>= 2; }
    return r;
}

__device__ __forceinline__ float2 cmul(float2 a, float2 b) {
    return make_float2(a.x * b.x - a.y * b.y, a.x * b.y + a.y * b.x);
}

// radix-4 DIT butterfly (twiddles pre-applied), e^{-2pi i/N} convention
__device__ __forceinline__ void bfly4(float2& x0, float2& x1, float2& x2, float2& x3) {
    float t0x = x0.x + x2.x, t0y = x0.y + x2.y;
    float t1x = x0.x - x2.x, t1y = x0.y - x2.y;
    float t2x = x1.x + x3.x, t2y = x1.y + x3.y;
    float t3x = x1.x - x3.x, t3y = x1.y - x3.y;
    x0 = make_float2(t0x + t2x, t0y + t2y);
    x1 = make_float2(t1x + t3y, t1y - t3x);   // t1 + (-i)*t3
    x2 = make_float2(t0x - t2x, t0y - t2y);
    x3 = make_float2(t1x - t3y, t1y + t3x);   // t1 + (+i)*t3
}

// Two consecutive radix-4 DIT stages (s with Q=4^s, then s+1) fused in
// registers.  Thread t owns the closed set {base + (a+4b)Q}, base=G*16Q+j,
// j=t%Q, G=t/Q.  Stage s: butterflies over a (twiddle angle -2pi*j/(4Q)).
// Stage s+1: butterflies over b (twiddle angle -2pi*(j+aQ)/(16Q)).
template <int Q>
__device__ __forceinline__ void stage_pair(float2* lds, int t) {
    const int j = t & (Q - 1);
    const int G = t / Q;
    const int base = G * 16 * Q + j;

    float2 v[4][4];
#pragma unroll
    for (int b = 0; b < 4; ++b)
#pragma unroll
        for (int a = 0; a < 4; ++a)
            v[a][b] = lds[SWZ(base + (a + 4 * b) * Q)];

    // stage s (over a); j==0 when Q==1 -> identity twiddles
    if (Q > 1) {
        float c1, s1;
        __sincosf((float)j * (-6.2831853071795864769f / (4.0f * (float)Q)), &s1, &c1);
        float2 w1 = make_float2(c1, s1);
        float2 w2 = cmul(w1, w1);
        float2 w3 = cmul(w2, w1);
#pragma unroll
        for (int b = 0; b < 4; ++b) {
            v[1][b] = cmul(v[1][b], w1);
            v[2][b] = cmul(v[2][b], w2);
            v[3][b] = cmul(v[3][b], w3);
        }
    }
#pragma unroll
    for (int b = 0; b < 4; ++b) bfly4(v[0][b], v[1][b], v[2][b], v[3][b]);

    // stage s+1 (over b): w(a) = u * E^a, u = e^{-2pi i j/(16Q)}, E = e^{-i pi/8}
    float2 u;
    if (Q == 1) {
        u = make_float2(1.0f, 0.0f);
    } else {
        float cu, su;
        __sincosf((float)j * (-6.2831853071795864769f / (16.0f * (float)Q)), &su, &cu);
        u = make_float2(cu, su);
    }
    const float2 E = make_float2(0.92387953251128674f, -0.38268343236508977f);
    float2 w = u;
#pragma unroll
    for (int a = 0; a < 4; ++a) {
        if (!(Q == 1 && a == 0)) {
            float2 W2 = cmul(w, w);
            float2 W3 = cmul(W2, w);
            v[a][1] = cmul(v[a][1], w);
            v[a][2] = cmul(v[a][2], W2);
            v[a][3] = cmul(v[a][3], W3);
        }
        bfly4(v[a][0], v[a][1], v[a][2], v[a][3]);
        if (a < 3) w = cmul(w, E);
    }

#pragma unroll
    for (int b = 0; b < 4; ++b)
#pragma unroll
        for (int a = 0; a < 4; ++a)
            lds[SWZ(base + (a + 4 * b) * Q)] = v[a][b];
}

__global__ __launch_bounds__(256)
void dct_rows2_kernel(const float* __restrict__ in, float* __restrict__ out) {
    // One 4096-point complex FFT per block = DCT of TWO real rows.
    __shared__ float2 lds[L];   // exactly 32 KB -> 5 blocks/CU

    const int r0 = blockIdx.x * 2;
    const int t = threadIdx.x;
    const float* rowA = in + (size_t)r0 * L;
    const float* rowB = rowA + L;

    // Makhoul reorder fused with digit reversal, float2 global loads:
    // v[n]=x[2n], v[4095-n]=x[2n+1] (n<2048); rev(4095-n)=4095-rev(n).
#pragma unroll
    for (int w = 0; w < 8; ++w) {
        int n = w * 256 + t;                 // n in [0,2048)
        float2 fa = *reinterpret_cast<const float2*>(&rowA[2 * n]);
        float2 fb = *reinterpret_cast<const float2*>(&rowB[2 * n]);
        int p = digitrev12(n);
        lds[SWZ(p)]        = make_float2(fa.x, fb.x);
        lds[SWZ(4095 - p)] = make_float2(fa.y, fb.y);
    }
    __syncthreads();

    stage_pair<1>(lds, t);      // stages 0,1
    __syncthreads();
    stage_pair<16>(lds, t);     // stages 2,3
    __syncthreads();
    stage_pair<256>(lds, t);    // stages 4,5
    __syncthreads();

    // Split packed spectrum and apply expk:
    //   A[k] = 0.5*(Z[k] + conj(Z[N-k])),  B[k] = -0.5i*(Z[k] - conj(Z[N-k]))
    //   y[k] = V.x*cos(th) + V.y*sin(th),  th = pi*k/8192
    float* outA = out + (size_t)r0 * L;
    float* outB = outA + L;
#pragma unroll
    for (int w = 0; w < 16; ++w) {
        int k = w * 256 + t;
        float2 Zk = lds[SWZ(k)];
        int m = (L - k) & (L - 1);
        float2 Zm = lds[SWZ(m)];

        float vax = 0.5f * (Zk.x + Zm.x);
        float vay = 0.5f * (Zk.y - Zm.y);
        float vbx = 0.5f * (Zk.y + Zm.y);
        float vby = 0.5f * (Zm.x - Zk.x);

        float th = (float)k * 3.8349519697141029e-4f;   // pi/8192
        float sk, ck;
        __sincosf(th, &sk, &ck);
        outA[k] = vax * ck + vay * sk;
        outB[k] = vbx * ck + vby * sk;
    }
}

__global__ __launch_bounds__(256)
void transpose_kernel(const float* __restrict__ in, float* __restrict__ out) {
    __shared__ float tile[32][33];
    const int bx = blockIdx.x, by = blockIdx.y;
    const int tx = threadIdx.x, ty = threadIdx.y;   // (32, 8)

#pragma unroll
    for (int i = 0; i < 32; i += 8) {
        tile[ty + i][tx] = in[(size_t)(by * 32 + ty + i) * L + bx * 32 + tx];
    }
    __syncthreads();
#pragma unroll
    for (int i = 0; i < 32; i += 8) {
        out[(size_t)(bx * 32 + ty + i) * L + by * 32 + tx] = tile[tx][ty + i];
    }
}

extern "C" void kernel_launch(void* const* d_in, const int* in_sizes, int n_in,
                              void* d_out, int out_size, void* d_ws, size_t ws_size,
                              hipStream_t stream) {
    const float* x = (const float*)d_in[0];
    float* out = (float*)d_out;
    float* ws  = (float*)d_ws;   // needs 64 MB

    dim3 tgrid(L / 32, L / 32);
    dim3 tblk(32, 8);

    dct_rows2_kernel<<<L / 2, 256, 0, stream>>>(x, out);
    transpose_kernel<<<tgrid, tblk, 0, stream>>>(out, ws);
    dct_rows2_kernel<<<L / 2, 256, 0, stream>>>(ws, ws);
    transpose_kernel<<<tgrid, tblk, 0, stream>>>(ws, out);
}

// Round 6
// 110.359 us; speedup vs baseline: 1.7076x; 1.0037x over previous
//
#include <hip/hip_runtime.h>
#include <hip/hip_bf16.h>

// 2D DCT-II (4096x4096 fp32), Makhoul reorder + radix-4 LDS FFT, 2 real rows
// per complex FFT.  Round 5: TWO complex FFTs (4 rows) per block in two 32KB
// LDS buffers -> twiddle/address/trig setup computed once, applied twice, and
// 2 independent dependency chains per thread (ILP hides LDS latency at the
// ~8 waves/CU the HW gives us).  XOR bank-swizzle phi(e)=e^(((e>>4)^(e>>8))&15)
// (R4: conflicts 8.1e6 -> 5.2e5).  float4 64x64-tile transpose.
// Plan: dct2(x->out) ; transpose(out->ws) ; dct2(ws->ws) ; transpose(ws->out).

#define L 4096

__device__ __forceinline__ int SWZ(int e) {
    return e ^ (((e >> 4) ^ (e >> 8)) & 15);
}

__device__ __forceinline__ int digitrev12(int n) {
    int r = 0;
#pragma unroll
    for (int i = 0; i < 6; ++i) { r = (r << 2) | (n & 3); n >>= 2; }
    return r;
}

__device__ __forceinline__ float2 cmul(float2 a, float2 b) {
    return make_float2(a.x * b.x - a.y * b.y, a.x * b.y + a.y * b.x);
}

// radix-4 DIT butterfly (twiddles pre-applied), e^{-2pi i/N} convention
__device__ __forceinline__ void bfly4(float2& x0, float2& x1, float2& x2, float2& x3) {
    float t0x = x0.x + x2.x, t0y = x0.y + x2.y;
    float t1x = x0.x - x2.x, t1y = x0.y - x2.y;
    float t2x = x1.x + x3.x, t2y = x1.y + x3.y;
    float t3x = x1.x - x3.x, t3y = x1.y - x3.y;
    x0 = make_float2(t0x + t2x, t0y + t2y);
    x1 = make_float2(t1x + t3y, t1y - t3x);   // t1 + (-i)*t3
    x2 = make_float2(t0x - t2x, t0y - t2y);
    x3 = make_float2(t1x - t3y, t1y + t3x);   // t1 + (+i)*t3
}

// Two consecutive radix-4 DIT stages fused in registers, applied to TWO
// independent FFT buffers with shared twiddles/addresses.
// Thread t owns {base + (a+4b)Q}, base = (t/Q)*16Q + (t%Q).
template <int Q>
__device__ __forceinline__ void stage_pair2(float2* __restrict__ lds0,
                                            float2* __restrict__ lds1, int t) {
    const int j = t & (Q - 1);
    const int G = t / Q;
    const int base = G * 16 * Q + j;

    int off[16];
#pragma unroll
    for (int i = 0; i < 16; ++i) off[i] = SWZ(base + i * Q);   // i = a + 4b

    float2 v0[4][4], v1[4][4];
#pragma unroll
    for (int b = 0; b < 4; ++b)
#pragma unroll
        for (int a = 0; a < 4; ++a) {
            v0[a][b] = lds0[off[a + 4 * b]];
            v1[a][b] = lds1[off[a + 4 * b]];
        }

    // stage s (over a); Q==1 -> j==0 -> identity twiddles
    if (Q > 1) {
        float c1, s1;
        __sincosf((float)j * (-6.2831853071795864769f / (4.0f * (float)Q)), &s1, &c1);
        float2 w1 = make_float2(c1, s1);
        float2 w2 = cmul(w1, w1);
        float2 w3 = cmul(w2, w1);
#pragma unroll
        for (int b = 0; b < 4; ++b) {
            v0[1][b] = cmul(v0[1][b], w1);  v1[1][b] = cmul(v1[1][b], w1);
            v0[2][b] = cmul(v0[2][b], w2);  v1[2][b] = cmul(v1[2][b], w2);
            v0[3][b] = cmul(v0[3][b], w3);  v1[3][b] = cmul(v1[3][b], w3);
        }
    }
#pragma unroll
    for (int b = 0; b < 4; ++b) {
        bfly4(v0[0][b], v0[1][b], v0[2][b], v0[3][b]);
        bfly4(v1[0][b], v1[1][b], v1[2][b], v1[3][b]);
    }

    // stage s+1 (over b): w(a) = u * E^a, u = e^{-2pi i j/(16Q)}, E = e^{-i pi/8}
    float2 u;
    if (Q == 1) {
        u = make_float2(1.0f, 0.0f);
    } else {
        float cu, su;
        __sincosf((float)j * (-6.2831853071795864769f / (16.0f * (float)Q)), &su, &cu);
        u = make_float2(cu, su);
    }
    const float2 E = make_float2(0.92387953251128674f, -0.38268343236508977f);
    float2 w = u;
#pragma unroll
    for (int a = 0; a < 4; ++a) {
        if (!(Q == 1 && a == 0)) {
            float2 W2 = cmul(w, w);
            float2 W3 = cmul(W2, w);
            v0[a][1] = cmul(v0[a][1], w);   v1[a][1] = cmul(v1[a][1], w);
            v0[a][2] = cmul(v0[a][2], W2);  v1[a][2] = cmul(v1[a][2], W2);
            v0[a][3] = cmul(v0[a][3], W3);  v1[a][3] = cmul(v1[a][3], W3);
        }
        bfly4(v0[a][0], v0[a][1], v0[a][2], v0[a][3]);
        bfly4(v1[a][0], v1[a][1], v1[a][2], v1[a][3]);
        if (a < 3) w = cmul(w, E);
    }

#pragma unroll
    for (int b = 0; b < 4; ++b)
#pragma unroll
        for (int a = 0; a < 4; ++a) {
            lds0[off[a + 4 * b]] = v0[a][b];
            lds1[off[a + 4 * b]] = v1[a][b];
        }
}

__global__ __launch_bounds__(256, 2)
void dct_rows4_kernel(const float* __restrict__ in, float* __restrict__ out) {
    // Two 4096-point complex FFTs per block = DCT of FOUR real rows.
    __shared__ float2 lds[2 * L];   // 64 KB -> 2 blocks/CU
    float2* lds0 = lds;
    float2* lds1 = lds + L;

    const int r0 = blockIdx.x * 4;
    const int t = threadIdx.x;
    const float* rowA = in + (size_t)r0 * L;
    const float* rowB = rowA + L;
    const float* rowC = rowB + L;
    const float* rowD = rowC + L;

    // Makhoul reorder fused with digit reversal, float2 global loads:
    // v[n]=x[2n], v[4095-n]=x[2n+1] (n<2048); rev(4095-n)=4095-rev(n).
#pragma unroll
    for (int w = 0; w < 8; ++w) {
        int n = w * 256 + t;                 // n in [0,2048)
        float2 fa = *reinterpret_cast<const float2*>(&rowA[2 * n]);
        float2 fb = *reinterpret_cast<const float2*>(&rowB[2 * n]);
        float2 fc = *reinterpret_cast<const float2*>(&rowC[2 * n]);
        float2 fd = *reinterpret_cast<const float2*>(&rowD[2 * n]);
        int p  = SWZ(digitrev12(n));
        int pm = SWZ(4095 - digitrev12(n));
        lds0[p]  = make_float2(fa.x, fb.x);
        lds0[pm] = make_float2(fa.y, fb.y);
        lds1[p]  = make_float2(fc.x, fd.x);
        lds1[pm] = make_float2(fc.y, fd.y);
    }
    __syncthreads();

    stage_pair2<1>(lds0, lds1, t);      // stages 0,1
    __syncthreads();
    stage_pair2<16>(lds0, lds1, t);     // stages 2,3
    __syncthreads();
    stage_pair2<256>(lds0, lds1, t);    // stages 4,5
    __syncthreads();

    // Split packed spectra and apply expk:
    //   A[k] = 0.5*(Z[k] + conj(Z[N-k])),  B[k] = -0.5i*(Z[k] - conj(Z[N-k]))
    //   y[k] = V.x*cos(th) + V.y*sin(th),  th = pi*k/8192
    float* outA = out + (size_t)r0 * L;
    float* outB = outA + L;
    float* outC = outB + L;
    float* outD = outC + L;
#pragma unroll
    for (int w = 0; w < 16; ++w) {
        int k = w * 256 + t;
        int m = (L - k) & (L - 1);
        int pk = SWZ(k), pm = SWZ(m);
        float th = (float)k * 3.8349519697141029e-4f;   // pi/8192
        float sk, ck;
        __sincosf(th, &sk, &ck);

        float2 Zk = lds0[pk];
        float2 Zm = lds0[pm];
        outA[k] = 0.5f * (Zk.x + Zm.x) * ck + 0.5f * (Zk.y - Zm.y) * sk;
        outB[k] = 0.5f * (Zk.y + Zm.y) * ck + 0.5f * (Zm.x - Zk.x) * sk;

        float2 Yk = lds1[pk];
        float2 Ym = lds1[pm];
        outC[k] = 0.5f * (Yk.x + Ym.x) * ck + 0.5f * (Yk.y - Ym.y) * sk;
        outD[k] = 0.5f * (Yk.y + Ym.y) * ck + 0.5f * (Ym.x - Yk.x) * sk;
    }
}

__global__ __launch_bounds__(256)
void transpose_kernel(const float* __restrict__ in, float* __restrict__ out) {
    // 64x64 tile, float4 global loads/stores, conflict-free LDS.
    __shared__ float tile[64][65];
    const int bx = blockIdx.x, by = blockIdx.y;
    const int tx = threadIdx.x & 15;        // 16 x float4 across a 64-col tile
    const int ty = threadIdx.x >> 4;        // 16 rows per pass

#pragma unroll
    for (int i = 0; i < 4; ++i) {
        int r = ty + 16 * i;
        float4 f = *reinterpret_cast<const float4*>(
            &in[(size_t)(by * 64 + r) * L + bx * 64 + tx * 4]);
        tile[r][tx * 4 + 0] = f.x;
        tile[r][tx * 4 + 1] = f.y;
        tile[r][tx * 4 + 2] = f.z;
        tile[r][tx * 4 + 3] = f.w;
    }
    __syncthreads();
#pragma unroll
    for (int i = 0; i < 4; ++i) {
        int r = ty + 16 * i;                // output row within tile
        float4 g = make_float4(tile[tx * 4 + 0][r], tile[tx * 4 + 1][r],
                               tile[tx * 4 + 2][r], tile[tx * 4 + 3][r]);
        *reinterpret_cast<float4*>(
            &out[(size_t)(bx * 64 + r) * L + by * 64 + tx * 4]) = g;
    }
}

extern "C" void kernel_launch(void* const* d_in, const int* in_sizes, int n_in,
                              void* d_out, int out_size, void* d_ws, size_t ws_size,
                              hipStream_t stream) {
    const float* x = (const float*)d_in[0];
    float* out = (float*)d_out;
    float* ws  = (float*)d_ws;   // needs 64 MB

    dim3 tgrid(L / 64, L / 64);

    dct_rows4_kernel<<<L / 4, 256, 0, stream>>>(x, out);
    transpose_kernel<<<tgrid, 256, 0, stream>>>(out, ws);
    dct_rows4_kernel<<<L / 4, 256, 0, stream>>>(ws, ws);
    transpose_kernel<<<tgrid, 256, 0, stream>>>(ws, out);
}